// Round 7
// baseline (538.203 us; speedup 1.0000x reference)
//
#include <hip/hip_runtime.h>

// Problem constants
#define BB 2
#define CC 64
#define KK 27
#define S_TOT 32768  // 32^3
#define BN_EPS 1e-5f

// ---------------------------------------------------------------------------
// Transpose kernel: x[b][c][s] -> xT[b][s][c]  (16.8 MB, LDS-tiled).
// ---------------------------------------------------------------------------
__global__ __launch_bounds__(256) void xpose_kernel(const float* __restrict__ x,
                                                    float* __restrict__ xT) {
  __shared__ float t[64 * 65];
  const int tid = threadIdx.x;
  const int blk = blockIdx.x;
  const int b   = blk >> 9;
  const int s0  = (blk & 511) << 6;
  const float* xb = x + ((size_t)b << 21);
  {
    const int cq = tid >> 4;
    const int sq = (tid & 15) << 2;
#pragma unroll
    for (int i = 0; i < 4; ++i) {
      int c = cq + (i << 4);
      float4 v = *(const float4*)(xb + ((size_t)c << 15) + s0 + sq);
      t[c * 65 + sq + 0] = v.x;
      t[c * 65 + sq + 1] = v.y;
      t[c * 65 + sq + 2] = v.z;
      t[c * 65 + sq + 3] = v.w;
    }
  }
  __syncthreads();
  {
    float* xTb = xT + ((size_t)b << 21);
    const int si = tid >> 2;
    const int cb = (tid & 3) << 4;
#pragma unroll
    for (int j = 0; j < 4; ++j) {
      int c = cb + (j << 2);
      float4 w;
      w.x = t[(c + 0) * 65 + si];
      w.y = t[(c + 1) * 65 + si];
      w.z = t[(c + 2) * 65 + si];
      w.w = t[(c + 3) * 65 + si];
      *(float4*)(xTb + ((size_t)(s0 + si) << 6) + c) = w;
    }
  }
}

// ---------------------------------------------------------------------------
// Fused main kernel. Block = 256 threads (4 waves) handles
// (b, group-half p, 64-wide spatial tile). Grid = 2*2*512 = 2048.
//   Phase 0: decode offset table offs[27][64] (u16, 0xFFFF = OOB) -> LDS
//   Phase 1: GEMM1 (w_reduce) + BN + ReLU -> sv[64][64] LDS
//   Phase 2: GEMM2 -> kreg[27] per-thread regs (wave w owns group g=4p+w)
//   Phase 3: gather-reduce from xT, FULL static unroll (partial unroll =
//            runtime kreg index = scratch spill, R6 disaster: 1.4 GB spill
//            traffic). Hoisting capped by sched_barrier(0) every 3rd k
//            (R5 showed unbounded pipelining -> 148 VGPR, 11% occupancy).
// LDS 19.4 KB; __launch_bounds__(256,6) caps VGPR at 85.
// ---------------------------------------------------------------------------
template <bool XT>
__global__ __launch_bounds__(256, 6) void invol_onepass(
    const float* __restrict__ x, const float* __restrict__ xTp,
    const float* __restrict__ wr, const float* __restrict__ wsp,
    const float* __restrict__ gamma, const float* __restrict__ beta,
    const float* __restrict__ mean, const float* __restrict__ var,
    float* __restrict__ out) {
  __shared__ float sv[CC * 64];            // 16 KB
  __shared__ unsigned short offs[KK * 64]; // 3.375 KB

  const int tid = threadIdx.x;
  const int blk = blockIdx.x;
  const int b   = blk >> 10;
  const int p   = (blk >> 9) & 1;
  const int s0  = (blk & 511) << 6;
  const int si  = tid & 63;
  const int w   = __builtin_amdgcn_readfirstlane(tid >> 6);  // wave 0..3
  const int g   = (p << 2) + w;                               // group 0..7

  const float* xb  = x + ((size_t)b << 21);
  const float* xs0 = xb + s0 + si;

  // ---- Phase 0: offset table ----
  // f = k*32768 + s, mixed radix [od:32][oh:32][ow:32][kd:3][kh:3][kw:3];
  // (dd,hh,ww) = (od+kd-1, oh+kh-1, ow+kw-1); 0xFFFF sentinel if OOB.
  for (int i = tid; i < KK * 64; i += 256) {
    int k  = i >> 6;
    int f  = (k << 15) + s0 + (i & 63);
    int kw = f % 3; int u = f / 3;
    int kh = u % 3; u /= 3;
    int kd = u % 3; u /= 3;
    int ww = (u & 31) + kw - 1; u >>= 5;
    int hh = (u & 31) + kh - 1; u >>= 5;
    int dd = u + kd - 1;
    unsigned short off = 0xFFFFu;
    if (((unsigned)ww < 32u) & ((unsigned)hh < 32u) & ((unsigned)dd < 32u))
      off = (unsigned short)((dd << 10) + (hh << 5) + ww);
    offs[i] = off;
  }

  // ---- Phase 1: GEMM1 + BN + ReLU -> sv ----
  {
    float acc[16];
#pragma unroll
    for (int j = 0; j < 16; ++j) acc[j] = 0.f;
#pragma unroll
    for (int half = 0; half < 2; ++half) {
      float xv[32];
#pragma unroll
      for (int c = 0; c < 32; ++c)
        xv[c] = xs0[(size_t)(half * 32 + c) << 15];
      const float* wrw = wr + (w * 16) * CC + half * 32;
#pragma unroll
      for (int j = 0; j < 16; ++j) {
        const float* r0 = wrw + j * CC;
        float a0 = 0.f, a1 = 0.f;
#pragma unroll
        for (int c = 0; c < 32; c += 2) {
          a0 = fmaf(r0[c],     xv[c],     a0);
          a1 = fmaf(r0[c + 1], xv[c + 1], a1);
        }
        acc[j] += a0 + a1;
      }
    }
#pragma unroll
    for (int j = 0; j < 16; ++j) {
      int o = w * 16 + j;
      float v = (acc[j] - mean[o]) * rsqrtf(var[o] + BN_EPS) * gamma[o] + beta[o];
      sv[o * 64 + si] = v > 0.f ? v : 0.f;
    }
  }
  __syncthreads();  // covers offs + sv

  // ---- Phase 2: GEMM2 -> kreg[27] (group g), registers only ----
  float kreg[27];
#pragma unroll
  for (int j = 0; j < KK; ++j) kreg[j] = 0.f;
#pragma unroll
  for (int e = 0; e < 8; ++e) {
    float xv[8];
#pragma unroll
    for (int c = 0; c < 8; ++c) xv[c] = sv[(e * 8 + c) * 64 + si];
    const float* wsw = wsp + (g * KK) * CC + e * 8;
#pragma unroll
    for (int j = 0; j < KK; ++j) {
      const float* r = wsw + j * CC;
      float a0 = 0.f, a1 = 0.f;
#pragma unroll
      for (int c = 0; c < 8; c += 2) {
        a0 = fmaf(r[c],     xv[c],     a0);
        a1 = fmaf(r[c + 1], xv[c + 1], a1);
      }
      kreg[j] += a0 + a1;
    }
  }

  // ---- Phase 3: involution gather-reduce (8 channels) ----
  {
    const int c0 = g << 3;
    float oacc[8];
#pragma unroll
    for (int i = 0; i < 8; ++i) oacc[i] = 0.f;

    if (XT) {
      const float* base = xTp + ((size_t)b << 21) + c0;
#pragma unroll
      for (int k = 0; k < KK; ++k) {   // FULL unroll: k is compile-time
        unsigned off = offs[(k << 6) + si];
        float kv = (off != 0xFFFFu) ? kreg[k] : 0.f;
        unsigned o2 = (off != 0xFFFFu) ? off : 0u;
        const float* xp = base + ((size_t)o2 << 6);
        float4 v0 = *(const float4*)xp;
        float4 v1 = *(const float4*)(xp + 4);
        oacc[0] = fmaf(kv, v0.x, oacc[0]);
        oacc[1] = fmaf(kv, v0.y, oacc[1]);
        oacc[2] = fmaf(kv, v0.z, oacc[2]);
        oacc[3] = fmaf(kv, v0.w, oacc[3]);
        oacc[4] = fmaf(kv, v1.x, oacc[4]);
        oacc[5] = fmaf(kv, v1.y, oacc[5]);
        oacc[6] = fmaf(kv, v1.z, oacc[6]);
        oacc[7] = fmaf(kv, v1.w, oacc[7]);
        if ((k % 3) == 2)  // folds at compile time; caps load hoisting
          __builtin_amdgcn_sched_barrier(0);
      }
    } else {
      const float* xc0 = xb + ((size_t)c0 << 15);
#pragma unroll
      for (int k = 0; k < KK; ++k) {
        unsigned off = offs[(k << 6) + si];
        float kv = kreg[k];
        if (off != 0xFFFFu) {
#pragma unroll
          for (int c8 = 0; c8 < 8; ++c8)
            oacc[c8] = fmaf(kv, xc0[off + (c8 << 15)], oacc[c8]);
        }
        if ((k % 3) == 2)
          __builtin_amdgcn_sched_barrier(0);
      }
    }

    float* ob = out + (((size_t)b * CC + c0) << 15) + s0 + si;
#pragma unroll
    for (int i = 0; i < 8; ++i) ob[(size_t)i << 15] = oacc[i];
  }
}

extern "C" void kernel_launch(void* const* d_in, const int* in_sizes, int n_in,
                              void* d_out, int out_size, void* d_ws, size_t ws_size,
                              hipStream_t stream) {
  const float* x     = (const float*)d_in[0];
  const float* wr    = (const float*)d_in[1];
  const float* wsp   = (const float*)d_in[2];
  const float* gamma = (const float*)d_in[3];
  const float* beta  = (const float*)d_in[4];
  const float* mean  = (const float*)d_in[5];
  const float* var   = (const float*)d_in[6];
  float* out = (float*)d_out;

  const size_t xt_bytes = (size_t)BB * S_TOT * CC * sizeof(float);  // 16.8 MB
  if (ws_size >= xt_bytes) {
    float* xT = (float*)d_ws;
    xpose_kernel<<<BB * (S_TOT / 64), 256, 0, stream>>>(x, xT);
    invol_onepass<true><<<BB * 2 * (S_TOT / 64), 256, 0, stream>>>(
        x, xT, wr, wsp, gamma, beta, mean, var, out);
  } else {
    invol_onepass<false><<<BB * 2 * (S_TOT / 64), 256, 0, stream>>>(
        x, nullptr, wr, wsp, gamma, beta, mean, var, out);
  }
}

// Round 8
// 284.499 us; speedup vs baseline: 1.8918x; 1.8918x over previous
//
#include <hip/hip_runtime.h>

// Problem constants
#define BB 2
#define CC 64
#define KK 27
#define S_TOT 32768  // 32^3
#define BN_EPS 1e-5f

// ws layout: xT[2][32768][64] floats (16.8 MB) then ker[2][216][32768] (56.6 MB)
#define XT_FLOATS ((size_t)BB * S_TOT * CC)

// ---------------------------------------------------------------------------
// K1: transpose x[b][c][s] -> xT[b][s][c]  (LDS-tiled, verified since R5).
// ---------------------------------------------------------------------------
__global__ __launch_bounds__(256) void xpose_kernel(const float* __restrict__ x,
                                                    float* __restrict__ xT) {
  __shared__ float t[64 * 65];
  const int tid = threadIdx.x;
  const int blk = blockIdx.x;
  const int b   = blk >> 9;
  const int s0  = (blk & 511) << 6;
  const float* xb = x + ((size_t)b << 21);
  {
    const int cq = tid >> 4;
    const int sq = (tid & 15) << 2;
#pragma unroll
    for (int i = 0; i < 4; ++i) {
      int c = cq + (i << 4);
      float4 v = *(const float4*)(xb + ((size_t)c << 15) + s0 + sq);
      t[c * 65 + sq + 0] = v.x;
      t[c * 65 + sq + 1] = v.y;
      t[c * 65 + sq + 2] = v.z;
      t[c * 65 + sq + 3] = v.w;
    }
  }
  __syncthreads();
  {
    float* xTb = xT + ((size_t)b << 21);
    const int si = tid >> 2;
    const int cb = (tid & 3) << 4;
#pragma unroll
    for (int j = 0; j < 4; ++j) {
      int c = cb + (j << 2);
      float4 w;
      w.x = t[(c + 0) * 65 + si];
      w.y = t[(c + 1) * 65 + si];
      w.z = t[(c + 2) * 65 + si];
      w.w = t[(c + 3) * 65 + si];
      *(float4*)(xTb + ((size_t)(s0 + si) << 6) + c) = w;
    }
  }
}

// ---------------------------------------------------------------------------
// K2: kernel generation = R4 phases 1-2 (VGPR=52, spill-free structure).
// Block (b, p, tile), 4 waves; wave w owns group g=4p+w, writes kreg[27]
// to ker[b][g*27+k][s] (wave-coalesced 256B stores).
// ---------------------------------------------------------------------------
__global__ __launch_bounds__(256, 8) void kergen_kernel(
    const float* __restrict__ x, const float* __restrict__ wr,
    const float* __restrict__ wsp, const float* __restrict__ gamma,
    const float* __restrict__ beta, const float* __restrict__ mean,
    const float* __restrict__ var, float* __restrict__ ker) {
  __shared__ float sv[CC * 64];  // 16 KB

  const int tid = threadIdx.x;
  const int blk = blockIdx.x;
  const int b   = blk >> 10;
  const int p   = (blk >> 9) & 1;
  const int s0  = (blk & 511) << 6;
  const int si  = tid & 63;
  const int w   = __builtin_amdgcn_readfirstlane(tid >> 6);
  const int g   = (p << 2) + w;

  const float* xs0 = x + ((size_t)b << 21) + s0 + si;

  // GEMM1 + BN + ReLU -> sv (wave w computes channels 16w..16w+15)
  {
    float acc[16];
#pragma unroll
    for (int j = 0; j < 16; ++j) acc[j] = 0.f;
#pragma unroll
    for (int half = 0; half < 2; ++half) {
      float xv[32];
#pragma unroll
      for (int c = 0; c < 32; ++c)
        xv[c] = xs0[(size_t)(half * 32 + c) << 15];
      const float* wrw = wr + (w * 16) * CC + half * 32;
#pragma unroll
      for (int j = 0; j < 16; ++j) {
        const float* r0 = wrw + j * CC;
        float a0 = 0.f, a1 = 0.f;
#pragma unroll
        for (int c = 0; c < 32; c += 2) {
          a0 = fmaf(r0[c],     xv[c],     a0);
          a1 = fmaf(r0[c + 1], xv[c + 1], a1);
        }
        acc[j] += a0 + a1;
      }
    }
#pragma unroll
    for (int j = 0; j < 16; ++j) {
      int o = w * 16 + j;
      float v = (acc[j] - mean[o]) * rsqrtf(var[o] + BN_EPS) * gamma[o] + beta[o];
      sv[o * 64 + si] = v > 0.f ? v : 0.f;
    }
  }
  __syncthreads();

  // GEMM2 -> kreg[27] (group g) -> store to ker
  float kreg[27];
#pragma unroll
  for (int j = 0; j < KK; ++j) kreg[j] = 0.f;
#pragma unroll
  for (int e = 0; e < 8; ++e) {
    float xv[8];
#pragma unroll
    for (int c = 0; c < 8; ++c) xv[c] = sv[(e * 8 + c) * 64 + si];
    const float* wsw = wsp + (g * KK) * CC + e * 8;
#pragma unroll
    for (int j = 0; j < KK; ++j) {
      const float* r = wsw + j * CC;
      float a0 = 0.f, a1 = 0.f;
#pragma unroll
      for (int c = 0; c < 8; c += 2) {
        a0 = fmaf(r[c],     xv[c],     a0);
        a1 = fmaf(r[c + 1], xv[c + 1], a1);
      }
      kreg[j] += a0 + a1;
    }
  }

  float* kb = ker + (((size_t)(b * 216 + g * KK)) << 15) + s0 + si;
#pragma unroll
  for (int k = 0; k < KK; ++k) kb[(size_t)k << 15] = kreg[k];
}

// ---------------------------------------------------------------------------
// K3: gather-reduce. NO kreg array -> k-loop stays ROLLED (runtime k legal:
// only LDS offs + scalars indexed by it; oacc[0..7] statically named).
// Pressure ~40 VGPR, hoisting structurally bounded by the loop.
// ker (56.6 MB) + xT (16.8 MB) are L3-resident -> L2/L3-BW kernel.
// ---------------------------------------------------------------------------
__global__ __launch_bounds__(256, 8) void gather_kernel(
    const float* __restrict__ xT, const float* __restrict__ ker,
    float* __restrict__ out) {
  __shared__ unsigned short offs[KK * 64];  // 3.375 KB

  const int tid = threadIdx.x;
  const int blk = blockIdx.x;
  const int b   = blk >> 10;
  const int p   = (blk >> 9) & 1;
  const int s0  = (blk & 511) << 6;
  const int si  = tid & 63;
  const int w   = __builtin_amdgcn_readfirstlane(tid >> 6);
  const int g   = (p << 2) + w;
  const int c0  = g << 3;

  // Offset table: f = k*32768 + s, mixed radix
  // [od:32][oh:32][ow:32][kd:3][kh:3][kw:3];
  // (dd,hh,ww) = (od+kd-1, oh+kh-1, ow+kw-1); 0xFFFF if OOB (zero pad).
  for (int i = tid; i < KK * 64; i += 256) {
    int k  = i >> 6;
    int f  = (k << 15) + s0 + (i & 63);
    int kw = f % 3; int u = f / 3;
    int kh = u % 3; u /= 3;
    int kd = u % 3; u /= 3;
    int ww = (u & 31) + kw - 1; u >>= 5;
    int hh = (u & 31) + kh - 1; u >>= 5;
    int dd = u + kd - 1;
    unsigned short off = 0xFFFFu;
    if (((unsigned)ww < 32u) & ((unsigned)hh < 32u) & ((unsigned)dd < 32u))
      off = (unsigned short)((dd << 10) + (hh << 5) + ww);
    offs[i] = off;
  }
  __syncthreads();

  const float* kb  = ker + (((size_t)(b * 216 + g * KK)) << 15) + s0 + si;
  const float* xTb = xT + ((size_t)b << 21) + c0;

  float oacc[8];
#pragma unroll
  for (int i = 0; i < 8; ++i) oacc[i] = 0.f;

#pragma unroll 2
  for (int k = 0; k < KK; ++k) {
    unsigned off = offs[(k << 6) + si];
    float kvr = kb[(size_t)k << 15];
    float kv  = (off != 0xFFFFu) ? kvr : 0.f;
    unsigned o2 = (off != 0xFFFFu) ? off : 0u;
    const float* xp = xTb + ((size_t)o2 << 6);
    float4 v0 = *(const float4*)xp;
    float4 v1 = *(const float4*)(xp + 4);
    oacc[0] = fmaf(kv, v0.x, oacc[0]);
    oacc[1] = fmaf(kv, v0.y, oacc[1]);
    oacc[2] = fmaf(kv, v0.z, oacc[2]);
    oacc[3] = fmaf(kv, v0.w, oacc[3]);
    oacc[4] = fmaf(kv, v1.x, oacc[4]);
    oacc[5] = fmaf(kv, v1.y, oacc[5]);
    oacc[6] = fmaf(kv, v1.z, oacc[6]);
    oacc[7] = fmaf(kv, v1.w, oacc[7]);
  }

  float* ob = out + (((size_t)b * CC + c0) << 15) + s0 + si;
#pragma unroll
  for (int i = 0; i < 8; ++i) ob[(size_t)i << 15] = oacc[i];
}

// ---------------------------------------------------------------------------
// Fallback (ws too small): exact R4 fused kernel — known-good 144 us.
// ---------------------------------------------------------------------------
__global__ __launch_bounds__(256, 8) void invol_fused(
    const float* __restrict__ x, const float* __restrict__ wr,
    const float* __restrict__ wsp, const float* __restrict__ gamma,
    const float* __restrict__ beta, const float* __restrict__ mean,
    const float* __restrict__ var, float* __restrict__ out) {
  __shared__ float sv[CC * 64];
  __shared__ int offs[KK * 64];

  const int tid = threadIdx.x;
  const int blk = blockIdx.x;
  const int b   = blk >> 10;
  const int p   = (blk >> 9) & 1;
  const int s0  = (blk & 511) << 6;
  const int si  = tid & 63;
  const int w   = __builtin_amdgcn_readfirstlane(tid >> 6);
  const int g   = (p << 2) + w;

  const float* xb  = x + ((size_t)b << 21);
  const float* xs0 = xb + s0 + si;

  for (int i = tid; i < KK * 64; i += 256) {
    int k  = i >> 6;
    int f  = (k << 15) + s0 + (i & 63);
    int kw = f % 3; int u = f / 3;
    int kh = u % 3; u /= 3;
    int kd = u % 3; u /= 3;
    int ww = (u & 31) + kw - 1; u >>= 5;
    int hh = (u & 31) + kh - 1; u >>= 5;
    int dd = u + kd - 1;
    int off = -1;
    if (((unsigned)ww < 32u) & ((unsigned)hh < 32u) & ((unsigned)dd < 32u))
      off = (dd << 10) + (hh << 5) + ww;
    offs[i] = off;
  }

  {
    float acc[16];
#pragma unroll
    for (int j = 0; j < 16; ++j) acc[j] = 0.f;
#pragma unroll
    for (int half = 0; half < 2; ++half) {
      float xv[32];
#pragma unroll
      for (int c = 0; c < 32; ++c)
        xv[c] = xs0[(size_t)(half * 32 + c) << 15];
      const float* wrw = wr + (w * 16) * CC + half * 32;
#pragma unroll
      for (int j = 0; j < 16; ++j) {
        const float* r0 = wrw + j * CC;
        float a0 = 0.f, a1 = 0.f;
#pragma unroll
        for (int c = 0; c < 32; c += 2) {
          a0 = fmaf(r0[c],     xv[c],     a0);
          a1 = fmaf(r0[c + 1], xv[c + 1], a1);
        }
        acc[j] += a0 + a1;
      }
    }
#pragma unroll
    for (int j = 0; j < 16; ++j) {
      int o = w * 16 + j;
      float v = (acc[j] - mean[o]) * rsqrtf(var[o] + BN_EPS) * gamma[o] + beta[o];
      sv[o * 64 + si] = v > 0.f ? v : 0.f;
    }
  }
  __syncthreads();

  float kreg[27];
#pragma unroll
  for (int j = 0; j < KK; ++j) kreg[j] = 0.f;
#pragma unroll
  for (int e = 0; e < 8; ++e) {
    float xv[8];
#pragma unroll
    for (int c = 0; c < 8; ++c) xv[c] = sv[(e * 8 + c) * 64 + si];
    const float* wsw = wsp + (g * KK) * CC + e * 8;
#pragma unroll
    for (int j = 0; j < KK; ++j) {
      const float* r = wsw + j * CC;
      float a0 = 0.f, a1 = 0.f;
#pragma unroll
      for (int c = 0; c < 8; c += 2) {
        a0 = fmaf(r[c],     xv[c],     a0);
        a1 = fmaf(r[c + 1], xv[c + 1], a1);
      }
      kreg[j] += a0 + a1;
    }
  }

  {
    const int c0 = g << 3;
    const float* xc0 = xb + ((size_t)c0 << 15);
    float oacc[8];
#pragma unroll
    for (int i = 0; i < 8; ++i) oacc[i] = 0.f;
#pragma unroll
    for (int k = 0; k < KK; ++k) {
      int off = offs[(k << 6) + si];
      float kv = kreg[k];
      if (off >= 0) {
#pragma unroll
        for (int c8 = 0; c8 < 8; ++c8)
          oacc[c8] = fmaf(kv, xc0[off + (c8 << 15)], oacc[c8]);
      }
    }
    float* ob = out + (((size_t)b * CC + c0) << 15) + s0 + si;
#pragma unroll
    for (int i = 0; i < 8; ++i) ob[(size_t)i << 15] = oacc[i];
  }
}

extern "C" void kernel_launch(void* const* d_in, const int* in_sizes, int n_in,
                              void* d_out, int out_size, void* d_ws, size_t ws_size,
                              hipStream_t stream) {
  const float* x     = (const float*)d_in[0];
  const float* wr    = (const float*)d_in[1];
  const float* wsp   = (const float*)d_in[2];
  const float* gamma = (const float*)d_in[3];
  const float* beta  = (const float*)d_in[4];
  const float* mean  = (const float*)d_in[5];
  const float* var   = (const float*)d_in[6];
  float* out = (float*)d_out;

  const size_t need = (XT_FLOATS + (size_t)BB * 216 * S_TOT) * sizeof(float);  // 73.4 MB
  if (ws_size >= need) {
    float* xT  = (float*)d_ws;
    float* ker = (float*)d_ws + XT_FLOATS;
    xpose_kernel<<<BB * (S_TOT / 64), 256, 0, stream>>>(x, xT);
    kergen_kernel<<<BB * 2 * (S_TOT / 64), 256, 0, stream>>>(
        x, wr, wsp, gamma, beta, mean, var, ker);
    gather_kernel<<<BB * 2 * (S_TOT / 64), 256, 0, stream>>>(xT, ker, out);
  } else {
    invol_fused<<<BB * 2 * (S_TOT / 64), 256, 0, stream>>>(
        x, wr, wsp, gamma, beta, mean, var, out);
  }
}